// Round 3
// baseline (160.159 us; speedup 1.0000x reference)
//
#include <hip/hip_runtime.h>

// Problem constants (fixed by the reference): B=512 rows, T=32768, K=64, R=4.
#define T_LEN  32768
#define B_ROWS 512
#define KSEL   64.0f
#define NTHR   1024      // threads per block = one row per block
#define CHUNK  32        // outputs per thread (NTHR*CHUNK == T_LEN)
#define HALO   10        // dependency cone of the 4 damping passes: 1+2+3+4
#define WLEN   (CHUNK + HALO)   // 42 live elements per thread

// sigmoid via v_exp_f32 + v_rcp_f32 (~1 ulp each; verified absmax 1.5e-05 vs np ref)
__device__ __forceinline__ float fast_sigmoid(float x) {
    return __builtin_amdgcn_rcpf(1.0f + __expf(-x));
}

// a * min(2/(1+a+b), 1):  2/(1+s) >= 1  <=>  s <= 1
__device__ __forceinline__ float damp(float a, float b) {
    float s = a + b;
    float f = (s > 1.0f) ? 2.0f * __builtin_amdgcn_rcpf(1.0f + s) : 1.0f;
    return a * f;
}

__global__ __launch_bounds__(NTHR, 4)   // cap VGPR at 128 -> 16 waves/CU
void selector_fused(const float* __restrict__ scores,
                    const float* __restrict__ log_temp,
                    float* __restrict__ out) {
    const int row  = blockIdx.x;
    const int tid  = threadIdx.x;
    const int col0 = tid << 5;                    // 32 outputs per thread
    const float* srow = scores + (size_t)row * T_LEN;

    float t = expf(log_temp[0]);
    const float inv_temp = 1.0f / fminf(fmaxf(t, 0.1f), 10.0f);

    // ---- Load chunk + halo ONCE into registers ----
    float w[44];
    if (col0 + WLEN <= T_LEN) {
        // col0 <= 32704 here, so reading 44 floats stays in-row (32704+44 <= 32768)
        const float4* p = (const float4*)(srow + col0);   // col0 % 32 == 0 -> aligned
        #pragma unroll
        for (int v = 0; v < 11; ++v) {
            float4 a = p[v];
            w[4*v + 0] = a.x; w[4*v + 1] = a.y; w[4*v + 2] = a.z; w[4*v + 3] = a.w;
        }
    } else {
        // only the last thread of each row wraps (jnp.roll semantics)
        #pragma unroll
        for (int j = 0; j < WLEN; ++j)
            w[j] = srow[(col0 + j) & (T_LEN - 1)];
        w[42] = 0.0f; w[43] = 0.0f;
    }

    // ---- Sigmoid (pre-scale) ----
    #pragma unroll
    for (int j = 0; j < WLEN; ++j)
        w[j] = fast_sigmoid(w[j] * inv_temp);

    // ---- Row budget: sum of sigmoid over OWNED elements only (each counted once) ----
    float sum = 0.0f;
    #pragma unroll
    for (int j = 0; j < CHUNK; ++j) sum += w[j];
    #pragma unroll
    for (int off = 32; off > 0; off >>= 1)
        sum += __shfl_down(sum, off, 64);
    __shared__ float red[NTHR / 64 + 1];          // 16 partials + broadcast slot
    const int wid = tid >> 6, lane = tid & 63;
    if (lane == 0) red[wid] = sum;
    __syncthreads();
    if (tid == 0) {
        float total = 0.0f;
        #pragma unroll
        for (int i = 0; i < NTHR / 64; ++i) total += red[i];
        red[NTHR / 64] = total;
    }
    __syncthreads();
    const float budget = fmaxf(red[NTHR / 64], 1e-6f);
    const float scale  = fminf(KSEL / budget, 1.0f);

    #pragma unroll
    for (int j = 0; j < WLEN; ++j) w[j] *= scale;

    // ---- Damping fast path: if max(y) <= 0.5 every factor is exactly 1 ----
    // (s = y_i + y_{i+d} <= 2*max <= 1  =>  min(2/(1+s),1) == 1; damping only
    //  shrinks values, so the slow branch is exact whenever taken)
    float m = 0.0f;
    #pragma unroll
    for (int j = 0; j < WLEN; ++j) m = fmaxf(m, w[j]);
    if (m > 0.5f) {
        #pragma unroll
        for (int j = 0; j < WLEN - 1; ++j) w[j] = damp(w[j], w[j + 1]);  // 42->41
        #pragma unroll
        for (int j = 0; j < WLEN - 3; ++j) w[j] = damp(w[j], w[j + 2]);  // 41->39
        #pragma unroll
        for (int j = 0; j < WLEN - 6; ++j) w[j] = damp(w[j], w[j + 3]);  // 39->36
        #pragma unroll
        for (int j = 0; j < CHUNK;    ++j) w[j] = damp(w[j], w[j + 4]);  // 36->32
    }

    if (col0 == 0) w[0] = 0.0f;   // y[:,0] = 0, applied after damping (ref order)

    float4* q = (float4*)(out + (size_t)row * T_LEN + col0);
    #pragma unroll
    for (int v = 0; v < 8; ++v)
        q[v] = make_float4(w[4*v + 0], w[4*v + 1], w[4*v + 2], w[4*v + 3]);
}

extern "C" void kernel_launch(void* const* d_in, const int* in_sizes, int n_in,
                              void* d_out, int out_size, void* d_ws, size_t ws_size,
                              hipStream_t stream) {
    const float* scores = (const float*)d_in[0];
    const float* lt     = (const float*)d_in[1];
    float*       out    = (float*)d_out;
    const int B = in_sizes[0] / T_LEN;   // 512 rows
    selector_fused<<<B, NTHR, 0, stream>>>(scores, lt, out);
}

// Round 4
// 121.223 us; speedup vs baseline: 1.3212x; 1.3212x over previous
//
#include <hip/hip_runtime.h>

// Problem constants (fixed by the reference): B=512 rows, T=32768, K=64, R=4.
#define T_LEN  32768
#define NTHR   512       // one row per block
#define KSEL   64.0f
#define CHUNK  16        // outputs per thread per sub-iteration (4 iters)
#define HALO   10        // dependency cone of the 4 damping passes: 1+2+3+4

// sigmoid via v_exp_f32 + v_rcp_f32 (~1 ulp each; verified absmax 1.5e-05 vs np ref)
__device__ __forceinline__ float fast_sigmoid(float x) {
    return __builtin_amdgcn_rcpf(1.0f + __expf(-x));
}

// a * min(2/(1+a+b), 1):  2/(1+s) >= 1  <=>  s <= 1
__device__ __forceinline__ float damp(float a, float b) {
    float s = a + b;
    float f = (s > 1.0f) ? 2.0f * __builtin_amdgcn_rcpf(1.0f + s) : 1.0f;
    return a * f;
}

// pack two fp32 -> bf16x2 with round-to-nearest-even (values in (0,1): no inf/nan)
__device__ __forceinline__ unsigned pack_bf16x2(float lo, float hi) {
    unsigned ul = __float_as_uint(lo), uh = __float_as_uint(hi);
    ul = (ul + 0x7FFFu + ((ul >> 16) & 1u)) >> 16;
    uh = (uh + 0x7FFFu + ((uh >> 16) & 1u)) >> 16;
    return ul | (uh << 16);
}

// LDS layout: 16384 bf16x2 pairs hold the row's sigmoids; padded 1 dword per
// 32 pairs so sweep-2 window reads (lane stride 128B unpadded = all lanes on
// one bank) spread across banks: dword index = p + (p>>5).
#define LDS_DWORDS (16384 + 512)

__global__ __launch_bounds__(NTHR, 4)   // cap VGPR 128 -> LDS-bound 2 blocks/CU
void selector_lds(const float* __restrict__ scores,
                  const float* __restrict__ log_temp,
                  float* __restrict__ out) {
    __shared__ unsigned ldsrow[LDS_DWORDS];
    __shared__ float red[NTHR / 64 + 1];

    const int row = blockIdx.x;
    const int tid = threadIdx.x;
    const float* srow = scores + (size_t)row * T_LEN;

    float t = expf(log_temp[0]);
    const float inv_temp = 1.0f / fminf(fmaxf(t, 0.1f), 10.0f);

    // ---- Sweep 1: coalesced read, sigmoid once per element, fp32 budget,
    //      stash sigmoid as bf16 pairs in LDS ----
    const float4* srow4 = (const float4*)srow;
    float sum = 0.0f;
    #pragma unroll
    for (int k = 0; k < 16; ++k) {
        float4 v = srow4[tid + NTHR * k];          // lane-contiguous: coalesced
        float s0 = fast_sigmoid(v.x * inv_temp);
        float s1 = fast_sigmoid(v.y * inv_temp);
        float s2 = fast_sigmoid(v.z * inv_temp);
        float s3 = fast_sigmoid(v.w * inv_temp);
        sum += (s0 + s1) + (s2 + s3);
        unsigned p0 = 2 * tid + 2 * NTHR * k;      // pair index of elem 4t+2048k
        unsigned p1 = p0 + 1;
        ldsrow[p0 + (p0 >> 5)] = pack_bf16x2(s0, s1);
        ldsrow[p1 + (p1 >> 5)] = pack_bf16x2(s2, s3);
    }

    // ---- Block reduction (barriers also publish the LDS row) ----
    #pragma unroll
    for (int off = 32; off > 0; off >>= 1)
        sum += __shfl_down(sum, off, 64);
    const int wid = tid >> 6, lane = tid & 63;
    if (lane == 0) red[wid] = sum;
    __syncthreads();
    if (tid == 0) {
        float total = 0.0f;
        #pragma unroll
        for (int i = 0; i < NTHR / 64; ++i) total += red[i];
        red[NTHR / 64] = total;
    }
    __syncthreads();
    const float budget = fmaxf(red[NTHR / 64], 1e-6f);
    const float scale  = fminf(KSEL / budget, 1.0f);

    // ---- Sweep 2: window from LDS, scale, damp (fast-path), coalesced store ----
    #pragma unroll
    for (int c = 0; c < 4; ++c) {
        const int W = CHUNK * tid + 8192 * c;      // even; 16 outputs from here
        const unsigned pbase = (unsigned)W >> 1;   // pair index
        float w[CHUNK + HALO];
        #pragma unroll
        for (int j = 0; j < 13; ++j) {             // 13 pairs = 26 elems (wrap via mask)
            unsigned q = (pbase + j) & 16383u;
            unsigned v = ldsrow[q + (q >> 5)];
            w[2 * j]     = __uint_as_float(v << 16) * scale;          // low bf16
            w[2 * j + 1] = __uint_as_float(v & 0xFFFF0000u) * scale;  // high bf16
        }

        // fast path: s = y_i + y_{i+d} <= 2*max <= 1  =>  factor == 1 exactly
        float m = 0.0f;
        #pragma unroll
        for (int j = 0; j < CHUNK + HALO; ++j) m = fmaxf(m, w[j]);
        if (m > 0.5f) {
            #pragma unroll
            for (int j = 0; j < 25; ++j) w[j] = damp(w[j], w[j + 1]);
            #pragma unroll
            for (int j = 0; j < 23; ++j) w[j] = damp(w[j], w[j + 2]);
            #pragma unroll
            for (int j = 0; j < 20; ++j) w[j] = damp(w[j], w[j + 3]);
            #pragma unroll
            for (int j = 0; j < 16; ++j) w[j] = damp(w[j], w[j + 4]);
        }

        if (W == 0) w[0] = 0.0f;   // y[:,0] = 0, applied after damping (ref order)

        float4* q4 = (float4*)(out + (size_t)row * T_LEN + W);
        q4[0] = make_float4(w[0],  w[1],  w[2],  w[3]);
        q4[1] = make_float4(w[4],  w[5],  w[6],  w[7]);
        q4[2] = make_float4(w[8],  w[9],  w[10], w[11]);
        q4[3] = make_float4(w[12], w[13], w[14], w[15]);
    }
}

extern "C" void kernel_launch(void* const* d_in, const int* in_sizes, int n_in,
                              void* d_out, int out_size, void* d_ws, size_t ws_size,
                              hipStream_t stream) {
    const float* scores = (const float*)d_in[0];
    const float* lt     = (const float*)d_in[1];
    float*       out    = (float*)d_out;
    const int B = in_sizes[0] / T_LEN;   // 512 rows
    selector_lds<<<B, NTHR, 0, stream>>>(scores, lt, out);
}

// Round 5
// 108.623 us; speedup vs baseline: 1.4745x; 1.1160x over previous
//
#include <hip/hip_runtime.h>

// Problem constants (fixed by the reference): B=512 rows, T=32768, K=64, R=4.
#define T_LEN  32768
#define NTHR   1024      // one row per block; 32 elems/thread
#define KSEL   64.0f

// sigmoid via v_exp_f32 + v_rcp_f32 (~1 ulp each; verified absmax 1.5e-05 vs np ref)
__device__ __forceinline__ float fast_sigmoid(float x) {
    return __builtin_amdgcn_rcpf(1.0f + __expf(-x));
}

// a * min(2/(1+a+b), 1):  2/(1+s) >= 1  <=>  s <= 1
__device__ __forceinline__ float damp(float a, float b) {
    float s = a + b;
    float f = (s > 1.0f) ? 2.0f * __builtin_amdgcn_rcpf(1.0f + s) : 1.0f;
    return a * f;
}

// Fast-path validity: if max(y) <= 0.5 over the whole row, then for every pass
// s = y_i + y_{i+d} <= 1  =>  factor min(2/(1+s),1) == 1 EXACTLY, and since
// pass outputs equal pass inputs the bound holds inductively for all 4 passes.
// Then out = scale * sigmoid(scores/temp) elementwise -- no neighbor windows.

__global__ __launch_bounds__(NTHR, 8)   // target VGPR<=64 -> 2 blocks/CU, 32 waves/CU
void selector_onepass(const float* __restrict__ scores,
                      const float* __restrict__ log_temp,
                      float* __restrict__ out) {
    const int row = blockIdx.x;
    const int tid = threadIdx.x;
    const float* srow = scores + (size_t)row * T_LEN;
    float*       orow = out    + (size_t)row * T_LEN;

    float t = expf(log_temp[0]);
    const float inv_temp = 1.0f / fminf(fmaxf(t, 0.1f), 10.0f);

    // ---- Phase 1: coalesced load (lane-contiguous float4), sigmoid in place ----
    const float4* p4 = (const float4*)srow;
    float4 s[8];
    #pragma unroll
    for (int k = 0; k < 8; ++k) s[k] = p4[tid + NTHR * k];

    float sum = 0.0f, mx = 0.0f;
    #pragma unroll
    for (int k = 0; k < 8; ++k) {
        s[k].x = fast_sigmoid(s[k].x * inv_temp);
        s[k].y = fast_sigmoid(s[k].y * inv_temp);
        s[k].z = fast_sigmoid(s[k].z * inv_temp);
        s[k].w = fast_sigmoid(s[k].w * inv_temp);
        sum += (s[k].x + s[k].y) + (s[k].z + s[k].w);
        mx = fmaxf(mx, fmaxf(fmaxf(s[k].x, s[k].y), fmaxf(s[k].z, s[k].w)));
    }

    // ---- Fused block reduction: sum and max ----
    #pragma unroll
    for (int off = 32; off > 0; off >>= 1) {
        sum += __shfl_down(sum, off, 64);
        mx   = fmaxf(mx, __shfl_down(mx, off, 64));
    }
    __shared__ float redS[NTHR / 64 + 1];
    __shared__ float redM[NTHR / 64 + 1];
    const int wid = tid >> 6, lane = tid & 63;
    if (lane == 0) { redS[wid] = sum; redM[wid] = mx; }
    __syncthreads();
    if (tid == 0) {
        float ts = 0.0f, tm = 0.0f;
        #pragma unroll
        for (int i = 0; i < NTHR / 64; ++i) { ts += redS[i]; tm = fmaxf(tm, redM[i]); }
        redS[NTHR / 64] = ts;
        redM[NTHR / 64] = tm;
    }
    __syncthreads();
    const float budget = fmaxf(redS[NTHR / 64], 1e-6f);
    const float scale  = fminf(KSEL / budget, 1.0f);
    const float rowmax = redM[NTHR / 64] * scale;    // block-uniform

    if (rowmax <= 0.5f) {
        // ---- Fast path (always taken for this data): out = scale * s, coalesced ----
        #pragma unroll
        for (int k = 0; k < 8; ++k) {
            s[k].x *= scale; s[k].y *= scale; s[k].z *= scale; s[k].w *= scale;
        }
        if (tid == 0) s[0].x = 0.0f;   // y[:,0] = 0 (element 0 lives in lane 0, k=0)
        float4* q4 = (float4*)orow;
        #pragma unroll
        for (int k = 0; k < 8; ++k) q4[tid + NTHR * k] = s[k];
    } else {
        // ---- Slow path (block-uniform, correct for any input; never taken here):
        //      per-thread contiguous 2x16-output windows, re-read + damp ----
        #pragma unroll
        for (int c = 0; c < 2; ++c) {
            const int col0 = 32 * tid + 16 * c;
            float w[26];
            #pragma unroll
            for (int j = 0; j < 26; ++j)
                w[j] = fast_sigmoid(srow[(col0 + j) & (T_LEN - 1)] * inv_temp) * scale;
            #pragma unroll
            for (int j = 0; j < 25; ++j) w[j] = damp(w[j], w[j + 1]);
            #pragma unroll
            for (int j = 0; j < 23; ++j) w[j] = damp(w[j], w[j + 2]);
            #pragma unroll
            for (int j = 0; j < 20; ++j) w[j] = damp(w[j], w[j + 3]);
            #pragma unroll
            for (int j = 0; j < 16; ++j) w[j] = damp(w[j], w[j + 4]);
            if (col0 == 0) w[0] = 0.0f;
            float4* q4 = (float4*)(orow + col0);
            q4[0] = make_float4(w[0],  w[1],  w[2],  w[3]);
            q4[1] = make_float4(w[4],  w[5],  w[6],  w[7]);
            q4[2] = make_float4(w[8],  w[9],  w[10], w[11]);
            q4[3] = make_float4(w[12], w[13], w[14], w[15]);
        }
    }
}

extern "C" void kernel_launch(void* const* d_in, const int* in_sizes, int n_in,
                              void* d_out, int out_size, void* d_ws, size_t ws_size,
                              hipStream_t stream) {
    const float* scores = (const float*)d_in[0];
    const float* lt     = (const float*)d_in[1];
    float*       out    = (float*)d_out;
    const int B = in_sizes[0] / T_LEN;   // 512 rows
    selector_onepass<<<B, NTHR, 0, stream>>>(scores, lt, out);
}